// Round 3
// baseline (5173.895 us; speedup 1.0000x reference)
//
#include <hip/hip_runtime.h>
#include <hip/hip_fp16.h>
#include <math.h>

// SO2_Attention — all-f32 problem (reference is jnp.float32 end to end).
// Pipeline: node e3nn linear (center+neigh) -> per-edge gather + Wigner rotate
// + channel product (sim 240) -> 3x latent GEMM (->384) + silu -> 384x256 GEMM
// + silu -> 256x128 GEMM -> out.
//
// Round 3: round-2 structure, fixed missing hip_fp16.h include.

#define NFEAT 240
#define EW 6            // edges per wave
#define WPB 4           // waves per block
#define EB (EW * WPB)   // 24 edges per block
#define BUFW 260        // sim(240)/h(256) union row, padded to 16B multiple

__device__ __forceinline__ float silu_f(float x) {
    return x / (1.0f + __expf(-x));
}

// ---------------- Kernel A: per-node e3nn linear (center + neigh) -------------
template <bool F32>
__global__ void node_kernel(const float* __restrict__ x,
                            const float* __restrict__ Wc0, const float* __restrict__ bc0,
                            const float* __restrict__ Wc1, const float* __restrict__ Wc2,
                            const float* __restrict__ Wn0, const float* __restrict__ bn0,
                            const float* __restrict__ Wn1, const float* __restrict__ Wn2,
                            void* __restrict__ Cp, void* __restrict__ Np,
                            int n_nodes)
{
    int t = blockIdx.x * blockDim.x + threadIdx.x;
    int total = n_nodes * NFEAT;
    if (t >= total) return;
    int n = t / NFEAT;
    int j = t - n * NFEAT;
    const float* xr = x + (size_t)n * NFEAT;
    float ac = 0.f, an = 0.f;
    if (j < 64) {
        #pragma unroll 8
        for (int m = 0; m < 64; ++m) {
            float xv = xr[m];
            ac = fmaf(xv, Wc0[m * 64 + j], ac);
            an = fmaf(xv, Wn0[m * 64 + j], an);
        }
        ac = ac * 0.125f + bc0[j];
        an = an * 0.125f + bn0[j];
    } else if (j < 160) {
        int s = j - 64; int k = s / 3; int d = s - 3 * k;
        #pragma unroll 8
        for (int m = 0; m < 32; ++m) {
            float xv = xr[64 + m * 3 + d];
            ac = fmaf(xv, Wc1[m * 32 + k], ac);
            an = fmaf(xv, Wn1[m * 32 + k], an);
        }
        const float s32 = 0.17677669529663687f; // 1/sqrt(32)
        ac *= s32; an *= s32;
    } else {
        int s = j - 160; int k = s / 5; int d = s - 5 * k;
        #pragma unroll 8
        for (int m = 0; m < 16; ++m) {
            float xv = xr[160 + m * 5 + d];
            ac = fmaf(xv, Wc2[m * 16 + k], ac);
            an = fmaf(xv, Wn2[m * 16 + k], an);
        }
        ac *= 0.25f; an *= 0.25f;
    }
    if (F32) {
        ((float*)Cp)[t] = ac;
        ((float*)Np)[t] = an;
    } else {
        ((__half*)Cp)[t] = __float2half(ac);
        ((__half*)Np)[t] = __float2half(an);
    }
}

// ---------------- Kernel B: fused per-edge pipeline ---------------------------
// 256 threads = 4 waves; each wave owns EW=6 consecutive edges.
template <bool F32>
__global__ __launch_bounds__(256) void edge_kernel(
    const void* __restrict__ Cp, const void* __restrict__ Np,
    const int* __restrict__ eidx, const float* __restrict__ wig,
    const float* __restrict__ Ws0, const float* __restrict__ bs0,
    const float* __restrict__ Ws1, const float* __restrict__ bs1,
    const float* __restrict__ Ws2, const float* __restrict__ bs2,
    const float* __restrict__ Wf1, const float* __restrict__ bf1,
    const float* __restrict__ Wf2, const float* __restrict__ bf2v,
    float* __restrict__ out, int n_edges)
{
    __shared__ __align__(16) float latS[WPB][EW][384];   // 36.9 KB
    __shared__ __align__(16) float bufS[WPB][EW][BUFW];  // 25.0 KB (sim then h)

    const int w = threadIdx.x >> 6;
    const int lane = threadIdx.x & 63;
    const long e0 = (long)blockIdx.x * EB + (long)w * EW;

    const float* Crow[EW];
    const float* Nrow[EW];
    const __half* Chrow[EW];
    const __half* Nhrow[EW];
    bool act[EW];
    #pragma unroll
    for (int e = 0; e < EW; ++e) {
        long eg = e0 + e;
        act[e] = eg < n_edges;
        long i0 = 0, i1 = 0;
        if (act[e]) { i0 = eidx[eg]; i1 = eidx[(long)n_edges + eg]; }
        if (F32) {
            Crow[e] = (const float*)Cp + i0 * NFEAT;
            Nrow[e] = (const float*)Np + i1 * NFEAT;
        } else {
            Chrow[e] = (const __half*)Cp + i0 * NFEAT;
            Nhrow[e] = (const __half*)Np + i1 * NFEAT;
        }
    }
    #define LDC(e, i) (F32 ? Crow[e][i] : __half2float(Chrow[e][i]))
    #define LDN(e, i) (F32 ? Nrow[e][i] : __half2float(Nhrow[e][i]))

    // ---- Phase 1: sim[e][0..240) directly into bufS ----
    #pragma unroll
    for (int e = 0; e < EW; ++e) {
        if (act[e]) {
            float c = LDC(e, lane);
            float n = LDN(e, lane);
            bufS[w][e][lane] = c * n;
        }
    }
    // l=1: tasks 6*32=192 -> 3 iters; e = t/32, m = t%32
    #pragma unroll
    for (int it = 0; it < 3; ++it) {
        int t = it * 64 + lane;
        int e = t >> 5;
        int m = t & 31;
        if (act[e]) {
            long eg = e0 + e;
            const float* wg = wig + eg * 81;
            int base = 64 + m * 3;
            float c0 = LDC(e, base + 0), c1 = LDC(e, base + 1), c2 = LDC(e, base + 2);
            float n0 = LDN(e, base + 0), n1 = LDN(e, base + 1), n2 = LDN(e, base + 2);
            #pragma unroll
            for (int q = 0; q < 3; ++q) {
                float r0 = wg[(1 + 0) * 9 + (1 + q)];
                float r1 = wg[(1 + 1) * 9 + (1 + q)];
                float r2 = wg[(1 + 2) * 9 + (1 + q)];
                float cq = c0 * r0 + c1 * r1 + c2 * r2;
                float nq = n0 * r0 + n1 * r1 + n2 * r2;
                bufS[w][e][base + q] = cq * nq;
            }
        }
    }
    // l=2: tasks 6*16=96 -> iter0: 64 lanes, iter1: 32 lanes
    #pragma unroll
    for (int it = 0; it < 2; ++it) {
        int t = it * 64 + lane;
        if (t < 96) {
            int e = t >> 4;
            int m = t & 15;
            if (act[e]) {
                long eg = e0 + e;
                const float* wg = wig + eg * 81;
                int base = 160 + m * 5;
                float c[5], n[5];
                #pragma unroll
                for (int d = 0; d < 5; ++d) { c[d] = LDC(e, base + d); n[d] = LDN(e, base + d); }
                #pragma unroll
                for (int q = 0; q < 5; ++q) {
                    float cq = 0.f, nq = 0.f;
                    #pragma unroll
                    for (int d = 0; d < 5; ++d) {
                        float rv = wg[(4 + d) * 9 + (4 + q)];
                        cq = fmaf(c[d], rv, cq);
                        nq = fmaf(n[d], rv, nq);
                    }
                    bufS[w][e][base + q] = cq * nq;
                }
            }
        }
    }
    __syncthreads();

    // ---- Phase 2: latent[e][0..384) = silu(sim @ Ws + bs) ----
    {
        const float* Wsl[3] = { Ws0, Ws1, Ws2 };
        const float* bsl[3] = { bs0, bs1, bs2 };
        const int Kl[3] = { 64, 96, 80 };
        const int offl[3] = { 0, 64, 160 };
        #pragma unroll
        for (int l = 0; l < 3; ++l) {
            const float* W = Wsl[l];
            const int K = Kl[l];
            const int off = offl[l];
            #pragma unroll
            for (int hh = 0; hh < 2; ++hh) {
                int kk = hh * 64 + lane;
                float acc[EW];
                float bias = bsl[l][kk];
                #pragma unroll
                for (int e = 0; e < EW; ++e) acc[e] = bias;
                for (int i0 = 0; i0 < K; i0 += 4) {
                    float w0 = W[(i0 + 0) * 128 + kk];
                    float w1 = W[(i0 + 1) * 128 + kk];
                    float w2 = W[(i0 + 2) * 128 + kk];
                    float w3 = W[(i0 + 3) * 128 + kk];
                    #pragma unroll
                    for (int e = 0; e < EW; ++e) {
                        float4 sv = *(const float4*)&bufS[w][e][off + i0];
                        acc[e] = fmaf(sv.x, w0, acc[e]);
                        acc[e] = fmaf(sv.y, w1, acc[e]);
                        acc[e] = fmaf(sv.z, w2, acc[e]);
                        acc[e] = fmaf(sv.w, w3, acc[e]);
                    }
                }
                #pragma unroll
                for (int e = 0; e < EW; ++e)
                    latS[w][e][l * 128 + kk] = silu_f(acc[e]);
            }
        }
    }
    __syncthreads();

    // ---- Phase 3: h[e][0..256) = silu(lat @ Wf1 + bf1) into bufS ----
    {
        int k0 = lane * 4;
        float4 acc[EW];
        float4 bias = *(const float4*)&bf1[k0];
        #pragma unroll
        for (int e = 0; e < EW; ++e) acc[e] = bias;
        for (int i0 = 0; i0 < 384; i0 += 4) {
            float4 w0 = *(const float4*)&Wf1[(size_t)(i0 + 0) * 256 + k0];
            float4 w1 = *(const float4*)&Wf1[(size_t)(i0 + 1) * 256 + k0];
            float4 w2 = *(const float4*)&Wf1[(size_t)(i0 + 2) * 256 + k0];
            float4 w3 = *(const float4*)&Wf1[(size_t)(i0 + 3) * 256 + k0];
            #pragma unroll
            for (int e = 0; e < EW; ++e) {
                float4 lv = *(const float4*)&latS[w][e][i0];
                acc[e].x = fmaf(lv.x, w0.x, acc[e].x); acc[e].x = fmaf(lv.y, w1.x, acc[e].x);
                acc[e].x = fmaf(lv.z, w2.x, acc[e].x); acc[e].x = fmaf(lv.w, w3.x, acc[e].x);
                acc[e].y = fmaf(lv.x, w0.y, acc[e].y); acc[e].y = fmaf(lv.y, w1.y, acc[e].y);
                acc[e].y = fmaf(lv.z, w2.y, acc[e].y); acc[e].y = fmaf(lv.w, w3.y, acc[e].y);
                acc[e].z = fmaf(lv.x, w0.z, acc[e].z); acc[e].z = fmaf(lv.y, w1.z, acc[e].z);
                acc[e].z = fmaf(lv.z, w2.z, acc[e].z); acc[e].z = fmaf(lv.w, w3.z, acc[e].z);
                acc[e].w = fmaf(lv.x, w0.w, acc[e].w); acc[e].w = fmaf(lv.y, w1.w, acc[e].w);
                acc[e].w = fmaf(lv.z, w2.w, acc[e].w); acc[e].w = fmaf(lv.w, w3.w, acc[e].w);
            }
        }
        __syncthreads();  // bufS sim no longer needed
        #pragma unroll
        for (int e = 0; e < EW; ++e) {
            float4 hv;
            hv.x = silu_f(acc[e].x); hv.y = silu_f(acc[e].y);
            hv.z = silu_f(acc[e].z); hv.w = silu_f(acc[e].w);
            *(float4*)&bufS[w][e][k0] = hv;
        }
    }
    __syncthreads();

    // ---- Phase 4: out[e][0..128) = h @ Wf2 + bf2 ----
    {
        int k0 = lane * 2;
        float2 acc[EW];
        float2 bias = *(const float2*)&bf2v[k0];
        #pragma unroll
        for (int e = 0; e < EW; ++e) acc[e] = bias;
        for (int i0 = 0; i0 < 256; i0 += 4) {
            float2 w0 = *(const float2*)&Wf2[(size_t)(i0 + 0) * 128 + k0];
            float2 w1 = *(const float2*)&Wf2[(size_t)(i0 + 1) * 128 + k0];
            float2 w2 = *(const float2*)&Wf2[(size_t)(i0 + 2) * 128 + k0];
            float2 w3 = *(const float2*)&Wf2[(size_t)(i0 + 3) * 128 + k0];
            #pragma unroll
            for (int e = 0; e < EW; ++e) {
                float4 hv = *(const float4*)&bufS[w][e][i0];
                acc[e].x = fmaf(hv.x, w0.x, acc[e].x); acc[e].x = fmaf(hv.y, w1.x, acc[e].x);
                acc[e].x = fmaf(hv.z, w2.x, acc[e].x); acc[e].x = fmaf(hv.w, w3.x, acc[e].x);
                acc[e].y = fmaf(hv.x, w0.y, acc[e].y); acc[e].y = fmaf(hv.y, w1.y, acc[e].y);
                acc[e].y = fmaf(hv.z, w2.y, acc[e].y); acc[e].y = fmaf(hv.w, w3.y, acc[e].y);
            }
        }
        #pragma unroll
        for (int e = 0; e < EW; ++e) {
            long eg = e0 + e;
            if (eg < n_edges) {
                out[eg * 128 + k0 + 0] = acc[e].x;
                out[eg * 128 + k0 + 1] = acc[e].y;
            }
        }
    }
    #undef LDC
    #undef LDN
}

extern "C" void kernel_launch(void* const* d_in, const int* in_sizes, int n_in,
                              void* d_out, int out_size, void* d_ws, size_t ws_size,
                              hipStream_t stream) {
    const float* x    = (const float*)d_in[0];
    // d_in[1] = active_edge_vector: unused by the reference
    const int* eidx   = (const int*)d_in[2];
    const float* wig  = (const float*)d_in[3];
    const float* Wc0  = (const float*)d_in[4];
    const float* bc0  = (const float*)d_in[5];
    const float* Wc1  = (const float*)d_in[6];
    const float* Wc2  = (const float*)d_in[7];
    const float* Wn0  = (const float*)d_in[8];
    const float* bn0  = (const float*)d_in[9];
    const float* Wn1  = (const float*)d_in[10];
    const float* Wn2  = (const float*)d_in[11];
    const float* Ws0  = (const float*)d_in[12];
    const float* bs0  = (const float*)d_in[13];
    const float* Ws1  = (const float*)d_in[14];
    const float* bs1  = (const float*)d_in[15];
    const float* Ws2  = (const float*)d_in[16];
    const float* bs2  = (const float*)d_in[17];
    const float* Wf1  = (const float*)d_in[18];
    const float* bf1  = (const float*)d_in[19];
    const float* Wf2  = (const float*)d_in[20];
    const float* bf2v = (const float*)d_in[21];
    float* out = (float*)d_out;

    const int n_nodes = in_sizes[0] / NFEAT;
    const int n_edges = in_sizes[2] / 2;
    const size_t cn = (size_t)n_nodes * NFEAT;

    const int blkA = 256;
    const int grdA = (int)((cn + blkA - 1) / blkA);
    const int grdB = (n_edges + EB - 1) / EB;

    if (ws_size >= cn * 2 * sizeof(float)) {
        float* C  = (float*)d_ws;
        float* Nh = C + cn;
        node_kernel<true><<<grdA, blkA, 0, stream>>>(x, Wc0, bc0, Wc1, Wc2,
                                                     Wn0, bn0, Wn1, Wn2,
                                                     (void*)C, (void*)Nh, n_nodes);
        edge_kernel<true><<<grdB, 256, 0, stream>>>((const void*)C, (const void*)Nh,
                                                    eidx, wig,
                                                    Ws0, bs0, Ws1, bs1, Ws2, bs2,
                                                    Wf1, bf1, Wf2, bf2v,
                                                    out, n_edges);
    } else {
        __half* C  = (__half*)d_ws;
        __half* Nh = C + cn;
        node_kernel<false><<<grdA, blkA, 0, stream>>>(x, Wc0, bc0, Wc1, Wc2,
                                                      Wn0, bn0, Wn1, Wn2,
                                                      (void*)C, (void*)Nh, n_nodes);
        edge_kernel<false><<<grdB, 256, 0, stream>>>((const void*)C, (const void*)Nh,
                                                     eidx, wig,
                                                     Ws0, bs0, Ws1, bs1, Ws2, bs2,
                                                     Wf1, bf1, Wf2, bf2v,
                                                     out, n_edges);
    }
}